// Round 1
// baseline (5320.557 us; speedup 1.0000x reference)
//
#include <hip/hip_runtime.h>
#include <math.h>

#define NFULL 2177   // 1 + L + S
#define NN    2176   // minor size (NFULL-1), = 34*64
#define NB    64
#define NMAT  8      // 4 batches x {z, target}
#define NBATCH 4

// ---------------- build phase ----------------

__global__ void init_cs_kernel(float* __restrict__ cs) {
  int i = blockIdx.x * blockDim.x + threadIdx.x;
  if (i < NMAT * NN) cs[i] = 0.f;
}

// Fused: writes off-diagonal M = -w for both masks while accumulating column
// sums (one atomic per thread per mask). Single pass over scores/zm/tm.
// Block: 256 threads = 256 columns; 64 rows per block (grid.y), batch grid.z.
__global__ __launch_bounds__(256) void build_fused(const float* __restrict__ scores,
                                                   const float* __restrict__ zm,
                                                   const float* __restrict__ tm,
                                                   const int* __restrict__ lengths,
                                                   float* __restrict__ cs,
                                                   float* __restrict__ M) {
  int c = blockIdx.x * 256 + threadIdx.x;   // minor column, node j = c+1
  if (c >= NN) return;
  int b = blockIdx.z;
  int len = lengths[b];
  int j = c + 1;
  bool jv = (j < len);
  int r0 = blockIdx.y * 64;                 // minor row base
  size_t sbase = (size_t)b * NFULL * NFULL + j;
  float az = 0.f, at = 0.f;
  if (blockIdx.y == 0 && jv) {              // i = 0 (root row): colsum only
    float e = __expf(scores[sbase]);
    az += e * zm[sbase];
    at += e * tm[sbase];
  }
  size_t mz = (size_t)b * NN * NN + (size_t)r0 * NN + c;
  size_t mt = (size_t)(NBATCH + b) * NN * NN + (size_t)r0 * NN + c;
  for (int rr = 0; rr < 64; ++rr) {
    int i = r0 + rr + 1;
    float vz = 0.f, vt = 0.f;
    if (jv && i < len) {
      size_t off = sbase + (size_t)i * NFULL;
      float e = __expf(scores[off]);
      vz = e * zm[off];
      vt = e * tm[off];
      az += vz;
      at += vt;
    }
    M[mz] = -vz;
    M[mt] = -vt;
    mz += NN;
    mt += NN;
  }
  if (az != 0.f) atomicAdd(&cs[b * NN + c], az);
  if (at != 0.f) atomicAdd(&cs[(NBATCH + b) * NN + c], at);
}

// diagonal: M[c][c] = colsum + pad (identity row/col for invalid nodes)
__global__ void diag_fix(const int* __restrict__ lengths,
                         const float* __restrict__ cs,
                         float* __restrict__ M) {
  int idx = blockIdx.x * 256 + threadIdx.x;
  if (idx >= NMAT * NN) return;
  int mm = idx / NN, c = idx - mm * NN;
  int len = lengths[mm & 3];
  float pad = (c + 1 < len) ? 0.f : 1.f;
  M[(size_t)mm * NN * NN + (size_t)c * NN + c] = cs[idx] + pad;
}

// ---------------- LU building blocks ----------------

// Factor the 64x64 block held in T (L unit-lower \ U upper), write it back to
// A at (k0,k0), and (if do_inv) compute invU = U^-1 and invL = L^-1 into X
// (reused for both) and store them to global. 256 threads. T,X are 64x68 LDS.
__device__ void factor_invert(float* __restrict__ A,
                              float* __restrict__ invUg,
                              float* __restrict__ invLg,
                              float (*T)[68], float (*X)[68],
                              float* __restrict__ Dinv,
                              int k0, int tid, int do_inv) {
  for (int j = 0; j < 63; ++j) {
    float inv = 1.0f / T[j][j];
    for (int r = j + 1 + tid; r < 64; r += 256) T[r][j] *= inv;
    __syncthreads();
    int rem = 63 - j;
    for (int idx = tid; idx < rem * rem; idx += 256) {
      int rr = j + 1 + idx / rem;
      int cc = j + 1 + idx % rem;
      T[rr][cc] -= T[rr][j] * T[j][cc];
    }
    __syncthreads();
  }
  for (int idx = tid; idx < 64 * 64; idx += 256) {
    int r = idx >> 6, c = idx & 63;
    A[(size_t)(k0 + r) * NN + (k0 + c)] = T[r][c];
  }
  if (!do_inv) return;
  if (tid < 64) Dinv[tid] = 1.0f / T[tid][tid];
  __syncthreads();
  // invU: column j solves U x = e_j (upper triangular back-substitution)
  if (tid < 64) {
    int j = tid;
    X[j][j] = Dinv[j];
    for (int i = j - 1; i >= 0; --i) {
      float s = 0.f;
      for (int t = i + 1; t <= j; ++t) s += T[i][t] * X[t][j];
      X[i][j] = -s * Dinv[i];
    }
    for (int i = j + 1; i < 64; ++i) X[i][j] = 0.f;
  }
  __syncthreads();
  for (int idx = tid; idx < 4096; idx += 256) invUg[idx] = X[idx >> 6][idx & 63];
  __syncthreads();
  // invL: column j solves L x = e_j (unit lower forward-substitution)
  if (tid < 64) {
    int j = tid;
    X[j][j] = 1.f;
    for (int i = j + 1; i < 64; ++i) {
      float s = 0.f;
      for (int t = j; t < i; ++t) s += T[i][t] * X[t][j];
      X[i][j] = -s;
    }
    for (int i = 0; i < j; ++i) X[i][j] = 0.f;
  }
  __syncthreads();
  for (int idx = tid; idx < 4096; idx += 256) invLg[idx] = X[idx >> 6][idx & 63];
}

// factor + invert diagonal block 0 (only standalone factor launch)
__global__ __launch_bounds__(256) void factor0(float* __restrict__ Mb,
                                               float* __restrict__ invUb,
                                               float* __restrict__ invLb) {
  __shared__ float T[64][68];
  __shared__ float X[64][68];
  __shared__ float Dinv[64];
  int m = blockIdx.x, tid = threadIdx.x;
  float* A = Mb + (size_t)m * NN * NN;
  for (int idx = tid; idx < 64 * 64; idx += 256) {
    int r = idx >> 6, c = idx & 63;
    T[r][c] = A[(size_t)r * NN + c];
  }
  __syncthreads();
  factor_invert(A, invUb + (size_t)m * 4096, invLb + (size_t)m * 4096,
                T, X, Dinv, 0, tid, 1);
}

// Panel update as GEMM: role 0 -> L21 = A21 * invU ; role 1 -> U12 = invL * A12
__global__ __launch_bounds__(256) void panel_gemm(float* __restrict__ Mb,
                                                  const float* __restrict__ invUb,
                                                  const float* __restrict__ invLb,
                                                  int k0) {
  __shared__ float Aa[64][68];  // Aa[k][r]
  __shared__ float Bb[64][68];  // Bb[k][c]
  int m = blockIdx.y, role = blockIdx.z, tid = threadIdx.x;
  float* A = Mb + (size_t)m * NN * NN;
  int obase = k0 + 64 + blockIdx.x * 64;
  if (role == 0) {
    const float* invU = invUb + (size_t)m * 4096;
    for (int idx = tid; idx < 4096; idx += 256) {
      int r = idx >> 6, k = idx & 63;
      Aa[k][r] = A[(size_t)(obase + r) * NN + (k0 + k)];
    }
    for (int idx = tid; idx < 4096; idx += 256)
      Bb[idx >> 6][idx & 63] = invU[idx];
  } else {
    const float* invL = invLb + (size_t)m * 4096;
    for (int idx = tid; idx < 4096; idx += 256) {
      int r = idx >> 6, k = idx & 63;
      Aa[k][r] = invL[(r << 6) + k];
    }
    for (int idx = tid; idx < 4096; idx += 256) {
      int k = idx >> 6, c = idx & 63;
      Bb[k][c] = A[(size_t)(k0 + k) * NN + (obase + c)];
    }
  }
  __syncthreads();
  int c0 = (tid & 15) << 2;
  int r0 = (tid >> 4) << 2;
  float acc[4][4];
#pragma unroll
  for (int i = 0; i < 4; ++i)
#pragma unroll
    for (int jj = 0; jj < 4; ++jj) acc[i][jj] = 0.f;
#pragma unroll 8
  for (int k = 0; k < 64; ++k) {
    float4 a  = *(const float4*)&Aa[k][r0];
    float4 bv = *(const float4*)&Bb[k][c0];
    acc[0][0] += a.x * bv.x; acc[0][1] += a.x * bv.y; acc[0][2] += a.x * bv.z; acc[0][3] += a.x * bv.w;
    acc[1][0] += a.y * bv.x; acc[1][1] += a.y * bv.y; acc[1][2] += a.y * bv.z; acc[1][3] += a.y * bv.w;
    acc[2][0] += a.z * bv.x; acc[2][1] += a.z * bv.y; acc[2][2] += a.z * bv.z; acc[2][3] += a.z * bv.w;
    acc[3][0] += a.w * bv.x; acc[3][1] += a.w * bv.y; acc[3][2] += a.w * bv.z; acc[3][3] += a.w * bv.w;
  }
  if (role == 0) {
#pragma unroll
    for (int i = 0; i < 4; ++i) {
      float4 v = make_float4(acc[i][0], acc[i][1], acc[i][2], acc[i][3]);
      *(float4*)&A[(size_t)(obase + r0 + i) * NN + (k0 + c0)] = v;
    }
  } else {
#pragma unroll
    for (int i = 0; i < 4; ++i) {
      float4 v = make_float4(acc[i][0], acc[i][1], acc[i][2], acc[i][3]);
      *(float4*)&A[(size_t)(k0 + r0 + i) * NN + (obase + c0)] = v;
    }
  }
}

// trailing update A22 -= L21*U12; the (0,0) tile block additionally factors
// the next diagonal block in LDS and computes its triangular inverses,
// hidden under the rest of the trailing update.
__global__ __launch_bounds__(256) void trail_gemm(float* __restrict__ Mb,
                                                  float* __restrict__ invUb,
                                                  float* __restrict__ invLb,
                                                  int k0, int do_inv) {
  __shared__ float Lt[64][68];  // Lt[k][r]
  __shared__ float Ut[64][68];  // Ut[k][c]
  __shared__ float Dinv[64];
  int m = blockIdx.z;
  float* A = Mb + (size_t)m * NN * NN;
  int base  = k0 + 64;
  int rbase = base + blockIdx.y * 64;
  int cbase = base + blockIdx.x * 64;
  int tid = threadIdx.x;
  for (int idx = tid; idx < 64 * 64; idx += 256) {
    int r = idx >> 6, k = idx & 63;
    Lt[k][r] = A[(size_t)(rbase + r) * NN + (k0 + k)];
  }
  for (int idx = tid; idx < 64 * 64; idx += 256) {
    int k = idx >> 6, c = idx & 63;
    Ut[k][c] = A[(size_t)(k0 + k) * NN + (cbase + c)];
  }
  __syncthreads();
  int c0 = (tid & 15) << 2;   // consecutive lanes -> consecutive columns
  int r0 = (tid >> 4) << 2;
  float acc[4][4];
#pragma unroll
  for (int i = 0; i < 4; ++i)
#pragma unroll
    for (int jj = 0; jj < 4; ++jj) acc[i][jj] = 0.f;
#pragma unroll 8
  for (int k = 0; k < 64; ++k) {
    float4 a  = *(const float4*)&Lt[k][r0];
    float4 bv = *(const float4*)&Ut[k][c0];
    acc[0][0] += a.x * bv.x; acc[0][1] += a.x * bv.y; acc[0][2] += a.x * bv.z; acc[0][3] += a.x * bv.w;
    acc[1][0] += a.y * bv.x; acc[1][1] += a.y * bv.y; acc[1][2] += a.y * bv.z; acc[1][3] += a.y * bv.w;
    acc[2][0] += a.z * bv.x; acc[2][1] += a.z * bv.y; acc[2][2] += a.z * bv.z; acc[2][3] += a.z * bv.w;
    acc[3][0] += a.w * bv.x; acc[3][1] += a.w * bv.y; acc[3][2] += a.w * bv.z; acc[3][3] += a.w * bv.w;
  }
  bool special = (blockIdx.x == 0 && blockIdx.y == 0);
  if (!special) {
#pragma unroll
    for (int i = 0; i < 4; ++i) {
      float4* p = (float4*)&A[(size_t)(rbase + r0 + i) * NN + (cbase + c0)];
      float4 v = *p;
      v.x -= acc[i][0]; v.y -= acc[i][1]; v.z -= acc[i][2]; v.w -= acc[i][3];
      *p = v;
    }
    return;
  }
  // special block: this tile IS the next diagonal block.
  __syncthreads();  // everyone done reading Lt/Ut before reuse as T
#pragma unroll
  for (int i = 0; i < 4; ++i) {
    const float4* p = (const float4*)&A[(size_t)(rbase + r0 + i) * NN + (cbase + c0)];
    float4 v = *p;
    v.x -= acc[i][0]; v.y -= acc[i][1]; v.z -= acc[i][2]; v.w -= acc[i][3];
    *(float4*)&Lt[r0 + i][c0] = v;  // T[r][c] tile (global write done by factor_invert)
  }
  __syncthreads();
  factor_invert(A, invUb + (size_t)m * 4096, invLb + (size_t)m * 4096,
                Lt, Ut, Dinv, base, tid, do_inv);
}

// ---------------- reduction ----------------

__global__ void logdet_kernel(const float* __restrict__ Mb, double* __restrict__ dlog) {
  int m = blockIdx.x;
  const float* A = Mb + (size_t)m * NN * NN;
  double s = 0.0;
  for (int i = threadIdx.x; i < NN; i += 256)
    s += (double)logf(fabsf(A[(size_t)i * NN + i]));
  __shared__ double red[256];
  red[threadIdx.x] = s;
  __syncthreads();
  for (int k = 128; k > 0; k >>= 1) {
    if (threadIdx.x < k) red[threadIdx.x] += red[threadIdx.x + k];
    __syncthreads();
  }
  if (threadIdx.x == 0) dlog[m] = red[0];
}

__global__ void final_kernel(const double* __restrict__ dlog, float* __restrict__ out) {
  if (threadIdx.x == 0) {
    double acc = 0.0;
    for (int b = 0; b < NBATCH; ++b) acc += dlog[b] - dlog[NBATCH + b];
    out[0] = (float)(acc * 0.25);
  }
}

// ---------------- launch ----------------

extern "C" void kernel_launch(void* const* d_in, const int* in_sizes, int n_in,
                              void* d_out, int out_size, void* d_ws, size_t ws_size,
                              hipStream_t stream) {
  const float* scores  = (const float*)d_in[0];
  const float* tm      = (const float*)d_in[1];  // target_mask
  const float* zm      = (const float*)d_in[2];  // z_mask
  const int*   lengths = (const int*)d_in[3];
  float* out = (float*)d_out;

  // ws layout: M (8*2176^2 f32) | cs (8*2176 f32) | dlog (8 f64) | invU | invL
  float* M  = (float*)d_ws;
  float* cs = M + (size_t)NMAT * NN * NN;
  double* dlog = (double*)(cs + (size_t)NMAT * NN);
  float* invU = (float*)(dlog + NMAT);
  float* invL = invU + (size_t)NMAT * 4096;

  init_cs_kernel<<<(NMAT * NN + 255) / 256, 256, 0, stream>>>(cs);
  build_fused<<<dim3((NN + 255) / 256, NN / 64, NBATCH), 256, 0, stream>>>(
      scores, zm, tm, lengths, cs, M);
  diag_fix<<<(NMAT * NN + 255) / 256, 256, 0, stream>>>(lengths, cs, M);
  factor0<<<NMAT, 256, 0, stream>>>(M, invU, invL);

  for (int k0 = 0; k0 + NB < NN; k0 += NB) {
    int rem = NN - k0 - NB;
    panel_gemm<<<dim3(rem / 64, NMAT, 2), 256, 0, stream>>>(M, invU, invL, k0);
    trail_gemm<<<dim3(rem / 64, rem / 64, NMAT), 256, 0, stream>>>(
        M, invU, invL, k0, rem > 64 ? 1 : 0);
  }

  logdet_kernel<<<NMAT, 256, 0, stream>>>(M, dlog);
  final_kernel<<<1, 64, 0, stream>>>(dlog, out);
}